// Round 5
// baseline (287.758 us; speedup 1.0000x reference)
//
#include <hip/hip_runtime.h>

typedef _Float16 half2_t __attribute__((ext_vector_type(2)));
typedef unsigned int uint_t;
typedef uint_t uint4v __attribute__((ext_vector_type(4)));

#define B_  64
#define T_  256
#define F_  16
#define H_  128

__device__ __forceinline__ float rcp_(float x)  { return __builtin_amdgcn_rcpf(x); }
__device__ __forceinline__ float sigm(float x)  { return rcp_(1.0f + __expf(-x)); }
__device__ __forceinline__ float tanh_(float x) { return 2.0f * rcp_(1.0f + __expf(-2.0f * x)) - 1.0f; }

#if __has_builtin(__builtin_amdgcn_fdot2)
__device__ __forceinline__ float dot2(uint_t w, uint_t h, float a) {
    return __builtin_amdgcn_fdot2(__builtin_bit_cast(half2_t, w),
                                  __builtin_bit_cast(half2_t, h), a, false);
}
#else
__device__ __forceinline__ float dot2(uint_t w, uint_t h, float a) {
    half2_t W = __builtin_bit_cast(half2_t, w), H = __builtin_bit_cast(half2_t, h);
    return a + (float)W[0] * (float)H[0] + (float)W[1] * (float)H[1];
}
#endif

// In-quad butterfly add via DPP. 0xB1 = quad_perm[1,0,3,2] (xor1), 0x4E = [2,3,0,1] (xor2).
template <int CTRL>
__device__ __forceinline__ float qadd(float v) {
    int t = __builtin_amdgcn_update_dpp(0, __builtin_bit_cast(int, v), CTRL, 0xF, 0xF, true);
    return v + __builtin_bit_cast(float, t);
}

// Kernel 0: LPT schedule. Sort batches desc by window length; task[r*16+f] = (f<<8)|b_rank_r.
// Worker w (512 blocks) runs tasks w and 1023-w -> long chains paired with short ones.
__global__ void make_sched(const int* __restrict__ index, unsigned short* __restrict__ task) {
    __shared__ int len[B_], ord[B_];
    const int t = threadIdx.x;            // 64 threads
    len[t] = index[2 * t + 1] - index[2 * t];
    ord[t] = t;
    __syncthreads();
    if (t == 0) {                          // stable insertion sort, desc
        for (int a = 1; a < B_; ++a) {
            int ob = ord[a], lb = len[ob], j = a - 1;
            while (j >= 0 && len[ord[j]] < lb) { ord[j + 1] = ord[j]; --j; }
            ord[j + 1] = ob;
        }
    }
    __syncthreads();
    const int b = ord[t];
#pragma unroll
    for (int f = 0; f < F_; ++f) task[t * F_ + f] = (unsigned short)((f << 8) | b);
}

// Kernel 1: repack W_hh [F,4H,H] fp32 -> f16-pair layout keyed to the main kernel's
// per-thread register file (thread (i,ks): rows {i+128m}, k-slice [32ks,32ks+32)).
__global__ void repack_w(const float* __restrict__ whh, uint_t* __restrict__ wt) {
    const int f = blockIdx.x, tid = threadIdx.x;
    const int i = tid >> 2, ks = tid & 3;
    const float* base = whh + (size_t)f * 512 * 128;
#pragma unroll
    for (int q = 0; q < 16; ++q) {
        uint_t tmp[4];
#pragma unroll
        for (int e = 0; e < 4; ++e) {
            int dd = q * 4 + e, m = dd >> 4, kk = dd & 15;
            int row = i + 128 * m, k0 = 32 * ks + 2 * kk;
            half2_t h = { (_Float16)base[row * 128 + k0], (_Float16)base[row * 128 + k0 + 1] };
            tmp[e] = __builtin_bit_cast(uint_t, h);
        }
        uint4 out = { tmp[0], tmp[1], tmp[2], tmp[3] };
        ((uint4*)wt)[((size_t)f * 16 + q) * 512 + tid] = out;
    }
}

// Kernel 2: 512 worker blocks x 512 threads; each runs 2 scheduled chains.
// launch_bounds(512,2): VGPR budget 256 so the allocator keeps the 64 weight dwords
// in arch VGPRs instead of AGPR-shuffling them every step (R4 failure: VGPR=48,
// ~240 instr/step vs ~85 ideal).
__global__ __launch_bounds__(512, 2) void lstm_main(
    const float* __restrict__ x, const int* __restrict__ index,
    const float* __restrict__ wih_g, const float* __restrict__ bias_g,
    const uint_t* __restrict__ wt, const unsigned short* __restrict__ task,
    float* __restrict__ hout)
{
    __shared__ float xsh[T_];
    __shared__ alignas(16) unsigned short hsh[2][H_];

    const int tid = threadIdx.x;
    const int i = tid >> 2;

    for (int s = 0; s < 2; ++s) {
        const int tk = (s == 0) ? blockIdx.x : (1023 - blockIdx.x);
        const int f = task[tk] >> 8, b = task[tk] & 255;

        // ---- opaque weight preload: 16 x global_load_dwordx4 into VGPRs ----
        uint4v w[16];
        {
            const char* src = (const char*)wt + (((size_t)f * 16) * 512 + tid) * 16;
#pragma unroll
            for (int q = 0; q < 16; ++q) {
                unsigned long long addr = (unsigned long long)(src + (size_t)q * 512 * 16);
                asm volatile("global_load_dwordx4 %0, %1, off" : "=v"(w[q]) : "v"(addr));
            }
            asm volatile("s_waitcnt vmcnt(0)");
            __builtin_amdgcn_sched_barrier(0);
        }

        float wih4[4], b4[4];
#pragma unroll
        for (int m = 0; m < 4; ++m) {
            wih4[m] = wih_g[f * 512 + 128 * m + i];
            b4[m]   = bias_g[f * 512 + 128 * m + i] * 0.25f;  // summed 4x by quad reduce
        }

        __syncthreads();                    // previous task's hsh reads done
        if (tid < T_) xsh[tid] = x[((size_t)b * T_ + tid) * F_ + f];
        if (tid < H_) hsh[0][tid] = 0;

        const int start = index[2 * b], end = index[2 * b + 1];
        float c = 0.0f, hval = 0.0f;
        int p = 0;

        for (int t = start; t < end; ++t) {
            __syncthreads();                // hsh[p] (and xsh on first iter) visible
            const uint4v* h4 = (const uint4v*)(&hsh[p][(tid & 3) * 32]);
            float acc[4] = { b4[0], b4[1], b4[2], b4[3] };
#pragma unroll
            for (int q = 0; q < 4; ++q) {
                uint4v hq = h4[q];
#pragma unroll
                for (int m = 0; m < 4; ++m) {
                    uint4v wq = w[m * 4 + q];
                    acc[m] = dot2(wq.x, hq.x, acc[m]);
                    acc[m] = dot2(wq.y, hq.y, acc[m]);
                    acc[m] = dot2(wq.z, hq.z, acc[m]);
                    acc[m] = dot2(wq.w, hq.w, acc[m]);
                }
            }
#pragma unroll
            for (int m = 0; m < 4; ++m) {
                acc[m] = qadd<0xB1>(acc[m]);
                acc[m] = qadd<0x4E>(acc[m]);
            }
            float xt = xsh[t];
            float pi = fmaf(xt, wih4[0], acc[0]);
            float pf = fmaf(xt, wih4[1], acc[1]);
            float pg = fmaf(xt, wih4[2], acc[2]);
            float po = fmaf(xt, wih4[3], acc[3]);
            float gi = sigm(pi), gf = sigm(pf), gg = tanh_(pg), go = sigm(po);
            c = fmaf(gf, c, gi * gg);
            hval = go * tanh_(c);
            if ((tid & 3) == 0) {
                _Float16 hf = (_Float16)hval;
                hsh[p ^ 1][i] = __builtin_bit_cast(unsigned short, hf);
            }
            p ^= 1;
        }
        if ((tid & 3) == 0) hout[((size_t)b * F_ + f) * H_ + i] = hval;
    }
}

// Kernel 3: per-batch epilogue: mean over H -> conv3 (pad 1) -> sigmoid gate -> gated fc.
__global__ void epilogue(const float* __restrict__ hout, const float* __restrict__ conv_w,
                         const float* __restrict__ fc_w, const float* __restrict__ fc_b,
                         float* __restrict__ out)
{
    const int b = blockIdx.x, t = threadIdx.x;   // 128 threads
    const int lane = t & 63, wv = t >> 6;
    __shared__ float part[2][16];
    __shared__ float gate_sh[16];

    float hv[16];
#pragma unroll
    for (int f = 0; f < 16; ++f) hv[f] = hout[((size_t)b * 16 + f) * 128 + t];

#pragma unroll
    for (int f = 0; f < 16; ++f) {
        float s = hv[f];
#pragma unroll
        for (int off = 32; off >= 1; off >>= 1) s += __shfl_down(s, off, 64);
        if (lane == 0) part[wv][f] = s;
    }
    __syncthreads();
    if (t < 16) gate_sh[t] = (part[0][t] + part[1][t]) * (1.0f / 128.0f);  // means
    __syncthreads();
    float gate = 0.0f;
    if (t < 16) {
        float l  = (t > 0)  ? gate_sh[t - 1] : 0.0f;
        float mi = gate_sh[t];
        float r  = (t < 15) ? gate_sh[t + 1] : 0.0f;
        gate = sigm(fmaf(l, conv_w[0], fmaf(mi, conv_w[1], r * conv_w[2])));
    }
    __syncthreads();
    if (t < 16) gate_sh[t] = gate;
    __syncthreads();

    float acc0 = 0.0f, acc1 = 0.0f;
    const float2* fw2 = (const float2*)fc_w;
#pragma unroll
    for (int f = 0; f < 16; ++f) {
        float hg = hv[f] * gate_sh[f];
        float2 w2 = fw2[f * 128 + t];
        acc0 = fmaf(hg, w2.x, acc0);
        acc1 = fmaf(hg, w2.y, acc1);
    }
#pragma unroll
    for (int off = 32; off >= 1; off >>= 1) {
        acc0 += __shfl_down(acc0, off, 64);
        acc1 += __shfl_down(acc1, off, 64);
    }
    if (lane == 0) { part[wv][0] = acc0; part[wv][1] = acc1; }
    __syncthreads();
    if (t == 0) {
        out[b * 2 + 0] = part[0][0] + part[1][0] + fc_b[0];
        out[b * 2 + 1] = part[0][1] + part[1][1] + fc_b[1];
    }
}

extern "C" void kernel_launch(void* const* d_in, const int* in_sizes, int n_in,
                              void* d_out, int out_size, void* d_ws, size_t ws_size,
                              hipStream_t stream) {
    const float* x      = (const float*)d_in[0];
    const int*   index  = (const int*)  d_in[1];
    const float* W_ih   = (const float*)d_in[2];
    const float* W_hh   = (const float*)d_in[3];
    const float* bias   = (const float*)d_in[4];
    const float* conv_w = (const float*)d_in[5];
    const float* fc_w   = (const float*)d_in[6];
    const float* fc_b   = (const float*)d_in[7];
    float* out = (float*)d_out;

    uint_t* wt   = (uint_t*)d_ws;                               // 2 MB
    float*  hout = (float*)((char*)d_ws + 2 * 1024 * 1024);     // 512 KB
    unsigned short* task = (unsigned short*)((char*)d_ws + 2 * 1024 * 1024 + 512 * 1024); // 2 KB

    make_sched<<<1, 64, 0, stream>>>(index, task);
    repack_w<<<F_, 512, 0, stream>>>(W_hh, wt);
    lstm_main<<<512, 512, 0, stream>>>(x, index, W_ih, bias, wt, task, hout);
    epilogue<<<B_, 128, 0, stream>>>(hout, conv_w, fc_w, fc_b, out);
}